// Round 1
// 4592.693 us; speedup vs baseline: 1.5188x; 1.5188x over previous
//
#include <hip/hip_runtime.h>
#include <math.h>

#define T_STEPS 512
#define B_SZ 8
#define D_SZ 512
#define N_SZ 64

// ---------------------------------------------------------------------------
// fast tanh via hardware exp; clamp avoids inf/inf NaN
__device__ __forceinline__ float tanh_fast(float x) {
    float cx = fminf(30.f, fmaxf(-30.f, x));
    float e = __expf(2.f * cx);
    return (e - 1.f) / (e + 1.f);
}

// ---------------------------------------------------------------------------
// proj_gemm: C[m,n] = sum_d A[m,d] * W[n,d] (+ bias[n])
// A: [M, D] row-major; W: [Nc, D] row-major; C: [M, Nc] row-major.
// BM=BN=64, BK=16, 256 threads, 4x4 micro-tile per thread.
__global__ __launch_bounds__(256)
void proj_gemm(const float* __restrict__ A, const float* __restrict__ W,
               const float* __restrict__ bias, float* __restrict__ C,
               int M, int Nc, int D) {
    __shared__ float As[16][64];
    __shared__ float Ws[16][64];
    const int m0 = blockIdx.x * 64;
    const int n0 = blockIdx.y * 64;
    const int tid = threadIdx.x;
    const int tx = tid & 15;        // n direction
    const int ty = tid >> 4;        // m direction
    const int lr = tid >> 2;        // 0..63 row within tile (for loading)
    const int lk = (tid & 3) * 4;   // k offset within tile

    float acc[4][4];
#pragma unroll
    for (int i = 0; i < 4; i++)
#pragma unroll
        for (int j = 0; j < 4; j++) acc[i][j] = 0.f;

    for (int kk = 0; kk < D; kk += 16) {
        float4 av = *(const float4*)&A[(size_t)(m0 + lr) * D + kk + lk];
        float4 wv = *(const float4*)&W[(size_t)(n0 + lr) * D + kk + lk];
        __syncthreads();
        As[lk + 0][lr] = av.x; As[lk + 1][lr] = av.y;
        As[lk + 2][lr] = av.z; As[lk + 3][lr] = av.w;
        Ws[lk + 0][lr] = wv.x; Ws[lk + 1][lr] = wv.y;
        Ws[lk + 2][lr] = wv.z; Ws[lk + 3][lr] = wv.w;
        __syncthreads();
#pragma unroll
        for (int k = 0; k < 16; k++) {
            float a0 = As[k][ty * 4 + 0], a1 = As[k][ty * 4 + 1];
            float a2 = As[k][ty * 4 + 2], a3 = As[k][ty * 4 + 3];
            float w0 = Ws[k][tx * 4 + 0], w1 = Ws[k][tx * 4 + 1];
            float w2 = Ws[k][tx * 4 + 2], w3 = Ws[k][tx * 4 + 3];
            acc[0][0] += a0 * w0; acc[0][1] += a0 * w1; acc[0][2] += a0 * w2; acc[0][3] += a0 * w3;
            acc[1][0] += a1 * w0; acc[1][1] += a1 * w1; acc[1][2] += a1 * w2; acc[1][3] += a1 * w3;
            acc[2][0] += a2 * w0; acc[2][1] += a2 * w1; acc[2][2] += a2 * w2; acc[2][3] += a2 * w3;
            acc[3][0] += a3 * w0; acc[3][1] += a3 * w1; acc[3][2] += a3 * w2; acc[3][3] += a3 * w3;
        }
    }

    float b0 = 0.f, b1 = 0.f, b2 = 0.f, b3 = 0.f;
    if (bias) {
        b0 = bias[n0 + tx * 4 + 0]; b1 = bias[n0 + tx * 4 + 1];
        b2 = bias[n0 + tx * 4 + 2]; b3 = bias[n0 + tx * 4 + 3];
    }
#pragma unroll
    for (int i = 0; i < 4; i++) {
        float4 ov;
        ov.x = acc[i][0] + b0; ov.y = acc[i][1] + b1;
        ov.z = acc[i][2] + b2; ov.w = acc[i][3] + b3;
        *(float4*)&C[(size_t)(m0 + ty * 4 + i) * Nc + n0 + tx * 4] = ov;
    }
}

// ---------------------------------------------------------------------------
// scan_kernel: one workgroup per batch b (8 WGs, 512 threads).
// Thread layout: n = tid>>3 (row 0..63), c = tid&7, d-chunk = c*64 .. c*64+63.
// State S[b,n,d] lives in registers. NO per-step S stores (that was the old
// bottleneck: the compiler's vmcnt(0)-before-barrier drained 128 KB/CU of
// stores every step). Instead we emit float2(alpha, g) per (t,b,n) — 8 B —
// and a separate massively-parallel kernel replays the (now linear)
// recurrence to materialize S at full-device bandwidth.
// sh_r is double-buffered on t&1 so only ONE barrier per step is needed.
__global__ __launch_bounds__(512)
void scan_kernel(const float* __restrict__ kp, const float* __restrict__ qp,
                 const float* __restrict__ wxp, const float* __restrict__ axp,
                 const float* __restrict__ S0, const float* __restrict__ W_r,
                 float* __restrict__ out_y, float2* __restrict__ coef) {
    const int b = blockIdx.x;
    const int tid = threadIdx.x;
    const int n = tid >> 3;
    const int c = tid & 7;
    const int d0 = c * 64;

    __shared__ float Wr_s[64 * 65];   // row stride 65: breaks 8-way bank conflict
    __shared__ float sh_r[2][64];     // double-buffered on t parity

    // stage W_r [N,N] into LDS (constant across steps)
    for (int i = tid; i < 64 * 64; i += 512) {
        int r = i >> 6, col = i & 63;
        Wr_s[r * 65 + col] = W_r[i];
    }

    // load S0 into registers (S[0] output slice is written by reconstruct_S)
    float s[64];
    {
        const float* s0p = S0 + ((size_t)b * N_SZ + n) * D_SZ + d0;
#pragma unroll
        for (int j = 0; j < 16; j++) {
            float4 v4 = *(const float4*)&s0p[j * 4];
            s[j * 4 + 0] = v4.x; s[j * 4 + 1] = v4.y;
            s[j * 4 + 2] = v4.z; s[j * 4 + 3] = v4.w;
        }
    }
    __syncthreads();  // Wr_s ready

    for (int t = 0; t < T_STEPS; t++) {
        const size_t tb = (size_t)t * B_SZ + b;
        // ---- load k_t AND q_t chunks up front: the pre-matvec barrier's
        //      vmcnt(0) drain hides q's latency for free ----
        float kr[64], qr[64];
        {
            const float* kt = kp + tb * D_SZ + d0;
            const float* qt = qp + tb * D_SZ + d0;
#pragma unroll
            for (int j = 0; j < 16; j++) {
                float4 kv = *(const float4*)&kt[j * 4];
                kr[j * 4 + 0] = kv.x; kr[j * 4 + 1] = kv.y;
                kr[j * 4 + 2] = kv.z; kr[j * 4 + 3] = kv.w;
            }
#pragma unroll
            for (int j = 0; j < 16; j++) {
                float4 qv = *(const float4*)&qt[j * 4];
                qr[j * 4 + 0] = qv.x; qr[j * 4 + 1] = qv.y;
                qr[j * 4 + 2] = qv.z; qr[j * 4 + 3] = qv.w;
            }
        }
        // ---- Sk[n] = S[n,:] . k ----
        float sk = 0.f;
#pragma unroll
        for (int j = 0; j < 64; j++) sk += s[j] * kr[j];
        sk += __shfl_xor(sk, 1, 64);
        sk += __shfl_xor(sk, 2, 64);
        sk += __shfl_xor(sk, 4, 64);
        float retr = tanh_fast(sk);
        if (c == 0) sh_r[t & 1][n] = retr;
        __syncthreads();   // the ONLY barrier per step

        // ---- v[n] = tanh( sum_m retr[m]*W_r[n,m] + wx + b ) ----
        float vp = 0.f;
#pragma unroll
        for (int j = 0; j < 8; j++) {
            int m = c * 8 + j;
            vp += sh_r[t & 1][m] * Wr_s[n * 65 + m];
        }
        vp += __shfl_xor(vp, 1, 64);
        vp += __shfl_xor(vp, 2, 64);
        vp += __shfl_xor(vp, 4, 64);
        float wx = wxp[tb * N_SZ + n];   // bias b folded in by proj_gemm
        float ax = axp[tb * N_SZ + n];   // bias b_alpha folded in
        float v = tanh_fast(vp + wx);
        float alpha = 1.f / (1.f + __expf(-ax));
        float g = (1.f - alpha) * v;

        // ---- state update: S = alpha*S + g*k (registers only) ----
#pragma unroll
        for (int j = 0; j < 64; j++) s[j] = alpha * s[j] + g * kr[j];

        // ---- y[n] = tanh( S_new[n,:] . q ) ----
        float yp = 0.f;
#pragma unroll
        for (int j = 0; j < 64; j++) yp += s[j] * qr[j];
        yp += __shfl_xor(yp, 1, 64);
        yp += __shfl_xor(yp, 2, 64);
        yp += __shfl_xor(yp, 4, 64);
        if (c == 0) {
            out_y[tb * N_SZ + n] = tanh_fast(yp);
            coef[tb * N_SZ + n] = make_float2(alpha, g);
        }
        // no trailing barrier: next step writes sh_r[(t+1)&1], and a wave can
        // only reach step t+2's write to sh_r[t&1] after ALL waves passed the
        // t+1 barrier, which is after their step-t reads of sh_r[t&1].
    }
}

// ---------------------------------------------------------------------------
// reconstruct_S: replay S_t[n,d] = alpha_t[n]*S_{t-1}[n,d] + g_t[n]*k_t[d]
// with known coefficients — elementwise-independent across (b,n,d).
// 65536 threads (256 blocks x 256), each owns one (b,n,d0:d0+3) strip.
// No barriers, no inter-thread deps: stores stream at device write BW.
// Wave lanes cover contiguous d for a fixed (b,n): k loads coalesced,
// coef load wave-uniform (L1 broadcast), stores 1 KB contiguous per wave.
__global__ __launch_bounds__(256)
void reconstruct_S(const float* __restrict__ kp, const float2* __restrict__ coef,
                   const float* __restrict__ S0, float* __restrict__ out_S) {
    const int tid = blockIdx.x * 256 + threadIdx.x;  // 0 .. 65535
    const int dq = tid & 127;          // d/4 within row
    const int n  = (tid >> 7) & 63;
    const int b  = tid >> 13;
    const size_t nd_off = ((size_t)b * N_SZ + n) * D_SZ + (size_t)dq * 4;
    const size_t step_S = (size_t)B_SZ * N_SZ * D_SZ;  // 262144 floats per t

    float4 s = *(const float4*)&S0[nd_off];
    *(float4*)&out_S[nd_off] = s;      // t = 0 slice
#pragma unroll 4
    for (int t = 0; t < T_STEPS; t++) {
        const size_t tb = (size_t)t * B_SZ + b;
        float2 ag = coef[tb * N_SZ + n];
        float4 kv = *(const float4*)&kp[tb * D_SZ + (size_t)dq * 4];
        s.x = ag.x * s.x + ag.y * kv.x;
        s.y = ag.x * s.y + ag.y * kv.y;
        s.z = ag.x * s.z + ag.y * kv.z;
        s.w = ag.x * s.w + ag.y * kv.w;
        *(float4*)&out_S[(size_t)(t + 1) * step_S + nd_off] = s;
    }
}

// ---------------------------------------------------------------------------
extern "C" void kernel_launch(void* const* d_in, const int* in_sizes, int n_in,
                              void* d_out, int out_size, void* d_ws, size_t ws_size,
                              hipStream_t stream) {
    const float* x       = (const float*)d_in[0];  // [T,B,D]
    const float* S0      = (const float*)d_in[1];  // [B,N,D]
    const float* W_k     = (const float*)d_in[2];  // [D,D]
    const float* W_q     = (const float*)d_in[3];  // [D,D]
    const float* W_x     = (const float*)d_in[4];  // [N,D]
    const float* W_r     = (const float*)d_in[5];  // [N,N]
    const float* b       = (const float*)d_in[6];  // [N]
    const float* W_alpha = (const float*)d_in[7];  // [N,D]
    const float* b_alpha = (const float*)d_in[8];  // [N]

    float* out_y = (float*)d_out;                              // [T,B,N]
    float* out_S = out_y + (size_t)T_STEPS * B_SZ * N_SZ;      // [T+1,B,N,D]

    const int M = T_STEPS * B_SZ;  // 4096
    float*  kp   = (float*)d_ws;                     // [M, D]
    float*  qp   = kp + (size_t)M * D_SZ;            // [M, D]
    float*  wxp  = qp + (size_t)M * D_SZ;            // [M, N]  (b folded)
    float*  axp  = wxp + (size_t)M * N_SZ;           // [M, N]  (b_alpha folded)
    float2* coef = (float2*)(axp + (size_t)M * N_SZ); // [M, N] float2(alpha, g)

    // projections
    {
        dim3 blk(256);
        dim3 gK(M / 64, D_SZ / 64);
        proj_gemm<<<gK, blk, 0, stream>>>(x, W_k, nullptr, kp, M, D_SZ, D_SZ);
        proj_gemm<<<gK, blk, 0, stream>>>(x, W_q, nullptr, qp, M, D_SZ, D_SZ);
        dim3 gN(M / 64, N_SZ / 64);
        proj_gemm<<<gN, blk, 0, stream>>>(x, W_x, b, wxp, M, N_SZ, D_SZ);
        proj_gemm<<<gN, blk, 0, stream>>>(x, W_alpha, b_alpha, axp, M, N_SZ, D_SZ);
    }

    // sequential scan: one workgroup per batch; emits y + (alpha,g) coefs only
    scan_kernel<<<dim3(B_SZ), dim3(512), 0, stream>>>(
        kp, qp, wxp, axp, S0, W_r, out_y, coef);

    // parallel replay of the (now linear) recurrence: writes all of out_S
    reconstruct_S<<<dim3((B_SZ * N_SZ * D_SZ / 4) / 256), dim3(256), 0, stream>>>(
        kp, coef, S0, out_S);
}

// Round 2
// 2004.739 us; speedup vs baseline: 3.4795x; 2.2909x over previous
//
#include <hip/hip_runtime.h>
#include <math.h>

#define T_STEPS 512
#define B_SZ 8
#define D_SZ 512
#define N_SZ 64

// ---------------------------------------------------------------------------
// fast tanh via hardware exp; clamp avoids inf/inf NaN
__device__ __forceinline__ float tanh_fast(float x) {
    float cx = fminf(30.f, fmaxf(-30.f, x));
    float e = __expf(2.f * cx);
    return (e - 1.f) / (e + 1.f);
}

// butterfly reduce over the 16-lane c-group (lanes differing in bits 0..3)
__device__ __forceinline__ float red16(float x) {
    x += __shfl_xor(x, 1, 64);
    x += __shfl_xor(x, 2, 64);
    x += __shfl_xor(x, 4, 64);
    x += __shfl_xor(x, 8, 64);
    return x;
}

// XOR swizzle for the 512-word k/q LDS buffers.
// Logical word L = c*32 + j*4 + e: without swizzle all 16 c-lanes of a
// ds_read_b128 hit banks {4j..4j+3} (16-way conflict, stride-128B pattern,
// guide §6 G4). XOR bits[7:5] into bits[4:2] -> 2-way (free). Involution,
// preserves 16B groups, bijective within 512 words.
__device__ __forceinline__ int swz(int w) {
    return w ^ (((w >> 5) & 7) << 2);
}

// ---------------------------------------------------------------------------
// proj_gemm: C[m,n] = sum_d A[m,d] * W[n,d] (+ bias[n])  (unchanged)
__global__ __launch_bounds__(256)
void proj_gemm(const float* __restrict__ A, const float* __restrict__ W,
               const float* __restrict__ bias, float* __restrict__ C,
               int M, int Nc, int D) {
    __shared__ float As[16][64];
    __shared__ float Ws[16][64];
    const int m0 = blockIdx.x * 64;
    const int n0 = blockIdx.y * 64;
    const int tid = threadIdx.x;
    const int tx = tid & 15;        // n direction
    const int ty = tid >> 4;        // m direction
    const int lr = tid >> 2;        // 0..63 row within tile (for loading)
    const int lk = (tid & 3) * 4;   // k offset within tile

    float acc[4][4];
#pragma unroll
    for (int i = 0; i < 4; i++)
#pragma unroll
        for (int j = 0; j < 4; j++) acc[i][j] = 0.f;

    for (int kk = 0; kk < D; kk += 16) {
        float4 av = *(const float4*)&A[(size_t)(m0 + lr) * D + kk + lk];
        float4 wv = *(const float4*)&W[(size_t)(n0 + lr) * D + kk + lk];
        __syncthreads();
        As[lk + 0][lr] = av.x; As[lk + 1][lr] = av.y;
        As[lk + 2][lr] = av.z; As[lk + 3][lr] = av.w;
        Ws[lk + 0][lr] = wv.x; Ws[lk + 1][lr] = wv.y;
        Ws[lk + 2][lr] = wv.z; Ws[lk + 3][lr] = wv.w;
        __syncthreads();
#pragma unroll
        for (int k = 0; k < 16; k++) {
            float a0 = As[k][ty * 4 + 0], a1 = As[k][ty * 4 + 1];
            float a2 = As[k][ty * 4 + 2], a3 = As[k][ty * 4 + 3];
            float w0 = Ws[k][tx * 4 + 0], w1 = Ws[k][tx * 4 + 1];
            float w2 = Ws[k][tx * 4 + 2], w3 = Ws[k][tx * 4 + 3];
            acc[0][0] += a0 * w0; acc[0][1] += a0 * w1; acc[0][2] += a0 * w2; acc[0][3] += a0 * w3;
            acc[1][0] += a1 * w0; acc[1][1] += a1 * w1; acc[1][2] += a1 * w2; acc[1][3] += a1 * w3;
            acc[2][0] += a2 * w0; acc[2][1] += a2 * w1; acc[2][2] += a2 * w2; acc[2][3] += a2 * w3;
            acc[3][0] += a3 * w0; acc[3][1] += a3 * w1; acc[3][2] += a3 * w2; acc[3][3] += a3 * w3;
        }
    }

    float b0 = 0.f, b1 = 0.f, b2 = 0.f, b3 = 0.f;
    if (bias) {
        b0 = bias[n0 + tx * 4 + 0]; b1 = bias[n0 + tx * 4 + 1];
        b2 = bias[n0 + tx * 4 + 2]; b3 = bias[n0 + tx * 4 + 3];
    }
#pragma unroll
    for (int i = 0; i < 4; i++) {
        float4 ov;
        ov.x = acc[i][0] + b0; ov.y = acc[i][1] + b1;
        ov.z = acc[i][2] + b2; ov.w = acc[i][3] + b3;
        *(float4*)&C[(size_t)(m0 + ty * 4 + i) * Nc + n0 + tx * 4] = ov;
    }
}

// ---------------------------------------------------------------------------
// scan_kernel v2: one 1024-thread block per batch (8 blocks, 16 waves/CU).
// Thread (n = tid>>4, c = tid&15) owns a 32-wide d-chunk of state row n.
// Per step (ONE barrier):
//   phase A (pre-barrier):
//     - register-prefetch 1 dword of k_{t+1}/q_{t+1} + next wx/ax
//     - ds_read_b128 k,q from swizzled double-buffered LDS
//     - sk = S.k, sq = S.q, kq = k.q  (kq makes y computable post-barrier
//       without q: y = tanh(alpha*sq + g*kq))
//     - retr -> sh_r;  ds_write prefetched k/q into other buffer
//   phase B (post-barrier):
//     - v = tanh(W_r.retr + wx)  (W_r fragment lives in 4 registers)
//     - alpha, g; state update; y & coef stores (c==0)
__global__ __launch_bounds__(1024)
void scan_kernel(const float* __restrict__ kp, const float* __restrict__ qp,
                 const float* __restrict__ wxp, const float* __restrict__ axp,
                 const float* __restrict__ S0, const float* __restrict__ W_r,
                 float* __restrict__ out_y, float2* __restrict__ coef) {
    const int b = blockIdx.x;
    const int tid = threadIdx.x;          // 0..1023
    const int n = tid >> 4;               // 0..63
    const int c = tid & 15;               // 0..15
    const int d0 = c * 32;

    __shared__ float bufK[2][512];
    __shared__ float bufQ[2][512];
    __shared__ float sh_r[2][64];

    // W_r fragment: constant across steps -> registers, no LDS staging
    const float wr0 = W_r[n * 64 + c * 4 + 0];
    const float wr1 = W_r[n * 64 + c * 4 + 1];
    const float wr2 = W_r[n * 64 + c * 4 + 2];
    const float wr3 = W_r[n * 64 + c * 4 + 3];

    // state chunk
    float s[32];
    {
        const float* s0p = S0 + ((size_t)b * N_SZ + n) * D_SZ + d0;
#pragma unroll
        for (int j = 0; j < 8; j++) {
            float4 v4 = *(const float4*)&s0p[j * 4];
            s[j * 4 + 0] = v4.x; s[j * 4 + 1] = v4.y;
            s[j * 4 + 2] = v4.z; s[j * 4 + 3] = v4.w;
        }
    }

    // prologue: fill buf[0] with k_0/q_0; preload wx/ax for t=0
    {
        float p0 = (tid < 512) ? kp[(size_t)b * D_SZ + tid]
                               : qp[(size_t)b * D_SZ + (tid - 512)];
        if (tid < 512) bufK[0][swz(tid)] = p0;
        else           bufQ[0][swz(tid - 512)] = p0;
    }
    float wxr = wxp[(size_t)b * N_SZ + n];
    float axr = axp[(size_t)b * N_SZ + n];
    __syncthreads();

    for (int t = 0; t < T_STEPS; t++) {
        const int cur = t & 1, nxt = cur ^ 1;
        const size_t tb = (size_t)t * B_SZ + b;
        const int t1 = (t + 1 < T_STEPS) ? (t + 1) : t;
        const size_t tb1 = (size_t)t1 * B_SZ + b;

        // ---- prefetch next step's inputs (latency hides under the dots) ----
        float pk  = (tid < 512) ? kp[tb1 * D_SZ + tid]
                                : qp[tb1 * D_SZ + (tid - 512)];
        float nwx = wxp[tb1 * N_SZ + n];
        float nax = axp[tb1 * N_SZ + n];

        // ---- k chunk + sk = S.k ----
        float kr[32];
        float sk0 = 0.f, sk1 = 0.f, sk2 = 0.f, sk3 = 0.f;
#pragma unroll
        for (int j = 0; j < 8; j++) {
            float4 kv = *(const float4*)&bufK[cur][swz(d0 + j * 4)];
            kr[j * 4 + 0] = kv.x; kr[j * 4 + 1] = kv.y;
            kr[j * 4 + 2] = kv.z; kr[j * 4 + 3] = kv.w;
            sk0 += s[j * 4 + 0] * kv.x; sk1 += s[j * 4 + 1] * kv.y;
            sk2 += s[j * 4 + 2] * kv.z; sk3 += s[j * 4 + 3] * kv.w;
        }
        // ---- stream q: sq = S.q, kq = k.q (q never crosses the barrier) ----
        float sq0 = 0.f, sq1 = 0.f, sq2 = 0.f, sq3 = 0.f;
        float kq0 = 0.f, kq1 = 0.f, kq2 = 0.f, kq3 = 0.f;
#pragma unroll
        for (int j = 0; j < 8; j++) {
            float4 qv = *(const float4*)&bufQ[cur][swz(d0 + j * 4)];
            sq0 += s[j * 4 + 0] * qv.x; sq1 += s[j * 4 + 1] * qv.y;
            sq2 += s[j * 4 + 2] * qv.z; sq3 += s[j * 4 + 3] * qv.w;
            kq0 += kr[j * 4 + 0] * qv.x; kq1 += kr[j * 4 + 1] * qv.y;
            kq2 += kr[j * 4 + 2] * qv.z; kq3 += kr[j * 4 + 3] * qv.w;
        }
        float sk = red16(sk0 + sk1 + sk2 + sk3);
        float sq = red16(sq0 + sq1 + sq2 + sq3);
        float kq = red16(kq0 + kq1 + kq2 + kq3);
        float retr = tanh_fast(sk);
        if (c == 0) sh_r[cur][n] = retr;

        // ---- stage next k/q into the other buffer (pre-barrier) ----
        if (tid < 512) bufK[nxt][swz(tid)] = pk;
        else           bufQ[nxt][swz(tid - 512)] = pk;

        __syncthreads();   // the ONLY barrier per step

        // ---- v[n] = tanh( sum_m retr[m]*W_r[n,m] + wx ) ----
        float4 rr = *(const float4*)&sh_r[cur][c * 4];
        float vp = red16(wr0 * rr.x + wr1 * rr.y + wr2 * rr.z + wr3 * rr.w);
        float v = tanh_fast(vp + wxr);
        float alpha = 1.f / (1.f + __expf(-axr));
        float g = (1.f - alpha) * v;

        // ---- state update: S = alpha*S + g*k ----
#pragma unroll
        for (int j = 0; j < 32; j++) s[j] = alpha * s[j] + g * kr[j];

        // ---- y = tanh(S_new.q) = tanh(alpha*(S.q) + g*(k.q)) ----
        if (c == 0) {
            out_y[tb * N_SZ + n] = tanh_fast(alpha * sq + g * kq);
            coef[tb * N_SZ + n] = make_float2(alpha, g);
        }
        wxr = nwx; axr = nax;
    }
}

// ---------------------------------------------------------------------------
// reconstruct_S: replay S_t[n,d] = alpha_t[n]*S_{t-1}[n,d] + g_t[n]*k_t[d]
// (unchanged — elementwise-parallel, streams 537 MB at device write BW)
__global__ __launch_bounds__(256)
void reconstruct_S(const float* __restrict__ kp, const float2* __restrict__ coef,
                   const float* __restrict__ S0, float* __restrict__ out_S) {
    const int tid = blockIdx.x * 256 + threadIdx.x;  // 0 .. 65535
    const int dq = tid & 127;          // d/4 within row
    const int n  = (tid >> 7) & 63;
    const int b  = tid >> 13;
    const size_t nd_off = ((size_t)b * N_SZ + n) * D_SZ + (size_t)dq * 4;
    const size_t step_S = (size_t)B_SZ * N_SZ * D_SZ;  // 262144 floats per t

    float4 s = *(const float4*)&S0[nd_off];
    *(float4*)&out_S[nd_off] = s;      // t = 0 slice
#pragma unroll 4
    for (int t = 0; t < T_STEPS; t++) {
        const size_t tb = (size_t)t * B_SZ + b;
        float2 ag = coef[tb * N_SZ + n];
        float4 kv = *(const float4*)&kp[tb * D_SZ + (size_t)dq * 4];
        s.x = ag.x * s.x + ag.y * kv.x;
        s.y = ag.x * s.y + ag.y * kv.y;
        s.z = ag.x * s.z + ag.y * kv.z;
        s.w = ag.x * s.w + ag.y * kv.w;
        *(float4*)&out_S[(size_t)(t + 1) * step_S + nd_off] = s;
    }
}

// ---------------------------------------------------------------------------
extern "C" void kernel_launch(void* const* d_in, const int* in_sizes, int n_in,
                              void* d_out, int out_size, void* d_ws, size_t ws_size,
                              hipStream_t stream) {
    const float* x       = (const float*)d_in[0];  // [T,B,D]
    const float* S0      = (const float*)d_in[1];  // [B,N,D]
    const float* W_k     = (const float*)d_in[2];  // [D,D]
    const float* W_q     = (const float*)d_in[3];  // [D,D]
    const float* W_x     = (const float*)d_in[4];  // [N,D]
    const float* W_r     = (const float*)d_in[5];  // [N,N]
    const float* b       = (const float*)d_in[6];  // [N]
    const float* W_alpha = (const float*)d_in[7];  // [N,D]
    const float* b_alpha = (const float*)d_in[8];  // [N]

    float* out_y = (float*)d_out;                              // [T,B,N]
    float* out_S = out_y + (size_t)T_STEPS * B_SZ * N_SZ;      // [T+1,B,N,D]

    const int M = T_STEPS * B_SZ;  // 4096
    float*  kp   = (float*)d_ws;                      // [M, D]
    float*  qp   = kp + (size_t)M * D_SZ;             // [M, D]
    float*  wxp  = qp + (size_t)M * D_SZ;             // [M, N]  (b folded)
    float*  axp  = wxp + (size_t)M * N_SZ;            // [M, N]  (b_alpha folded)
    float2* coef = (float2*)(axp + (size_t)M * N_SZ); // [M, N] float2(alpha, g)

    // projections
    {
        dim3 blk(256);
        dim3 gK(M / 64, D_SZ / 64);
        proj_gemm<<<gK, blk, 0, stream>>>(x, W_k, nullptr, kp, M, D_SZ, D_SZ);
        proj_gemm<<<gK, blk, 0, stream>>>(x, W_q, nullptr, qp, M, D_SZ, D_SZ);
        dim3 gN(M / 64, N_SZ / 64);
        proj_gemm<<<gN, blk, 0, stream>>>(x, W_x, b, wxp, M, N_SZ, D_SZ);
        proj_gemm<<<gN, blk, 0, stream>>>(x, W_alpha, b_alpha, axp, M, N_SZ, D_SZ);
    }

    // sequential scan: one 1024-thread workgroup per batch
    scan_kernel<<<dim3(B_SZ), dim3(1024), 0, stream>>>(
        kp, qp, wxp, axp, S0, W_r, out_y, coef);

    // parallel replay of the (now linear) recurrence: writes all of out_S
    reconstruct_S<<<dim3((B_SZ * N_SZ * D_SZ / 4) / 256), dim3(256), 0, stream>>>(
        kp, coef, S0, out_S);
}

// Round 3
// 1719.885 us; speedup vs baseline: 4.0558x; 1.1656x over previous
//
#include <hip/hip_runtime.h>
#include <math.h>

#define T_STEPS 512
#define B_SZ 8
#define D_SZ 512
#define N_SZ 64

// ---------------------------------------------------------------------------
// fast tanh via hardware exp; clamp avoids inf/inf NaN
__device__ __forceinline__ float tanh_fast(float x) {
    float cx = fminf(30.f, fmaxf(-30.f, x));
    float e = __expf(2.f * cx);
    return (e - 1.f) / (e + 1.f);
}

// butterfly reduce over the 16-lane c-group (lanes differing in bits 0..3)
__device__ __forceinline__ float red16(float x) {
    x += __shfl_xor(x, 1, 64);
    x += __shfl_xor(x, 2, 64);
    x += __shfl_xor(x, 4, 64);
    x += __shfl_xor(x, 8, 64);
    return x;
}

// XOR swizzle for the 512-word k/q LDS buffers.
// Logical word L = c*32 + j*4 + e: without swizzle all 16 c-lanes of a
// ds_read_b128 hit banks {4j..4j+3} (16-way conflict). XOR bits[7:5] into
// bits[4:2] -> 2-way (free, m136). Involution, preserves 16B groups.
__device__ __forceinline__ int swz(int w) {
    return w ^ (((w >> 5) & 7) << 2);
}

// ---------------------------------------------------------------------------
// proj_gemm: C[m,n] = sum_d A[m,d] * W[n,d] (+ bias[n])  (unchanged)
__global__ __launch_bounds__(256)
void proj_gemm(const float* __restrict__ A, const float* __restrict__ W,
               const float* __restrict__ bias, float* __restrict__ C,
               int M, int Nc, int D) {
    __shared__ float As[16][64];
    __shared__ float Ws[16][64];
    const int m0 = blockIdx.x * 64;
    const int n0 = blockIdx.y * 64;
    const int tid = threadIdx.x;
    const int tx = tid & 15;        // n direction
    const int ty = tid >> 4;        // m direction
    const int lr = tid >> 2;        // 0..63 row within tile (for loading)
    const int lk = (tid & 3) * 4;   // k offset within tile

    float acc[4][4];
#pragma unroll
    for (int i = 0; i < 4; i++)
#pragma unroll
        for (int j = 0; j < 4; j++) acc[i][j] = 0.f;

    for (int kk = 0; kk < D; kk += 16) {
        float4 av = *(const float4*)&A[(size_t)(m0 + lr) * D + kk + lk];
        float4 wv = *(const float4*)&W[(size_t)(n0 + lr) * D + kk + lk];
        __syncthreads();
        As[lk + 0][lr] = av.x; As[lk + 1][lr] = av.y;
        As[lk + 2][lr] = av.z; As[lk + 3][lr] = av.w;
        Ws[lk + 0][lr] = wv.x; Ws[lk + 1][lr] = wv.y;
        Ws[lk + 2][lr] = wv.z; Ws[lk + 3][lr] = wv.w;
        __syncthreads();
#pragma unroll
        for (int k = 0; k < 16; k++) {
            float a0 = As[k][ty * 4 + 0], a1 = As[k][ty * 4 + 1];
            float a2 = As[k][ty * 4 + 2], a3 = As[k][ty * 4 + 3];
            float w0 = Ws[k][tx * 4 + 0], w1 = Ws[k][tx * 4 + 1];
            float w2 = Ws[k][tx * 4 + 2], w3 = Ws[k][tx * 4 + 3];
            acc[0][0] += a0 * w0; acc[0][1] += a0 * w1; acc[0][2] += a0 * w2; acc[0][3] += a0 * w3;
            acc[1][0] += a1 * w0; acc[1][1] += a1 * w1; acc[1][2] += a1 * w2; acc[1][3] += a1 * w3;
            acc[2][0] += a2 * w0; acc[2][1] += a2 * w1; acc[2][2] += a2 * w2; acc[2][3] += a2 * w3;
            acc[3][0] += a3 * w0; acc[3][1] += a3 * w1; acc[3][2] += a3 * w2; acc[3][3] += a3 * w3;
        }
    }

    float b0 = 0.f, b1 = 0.f, b2 = 0.f, b3 = 0.f;
    if (bias) {
        b0 = bias[n0 + tx * 4 + 0]; b1 = bias[n0 + tx * 4 + 1];
        b2 = bias[n0 + tx * 4 + 2]; b3 = bias[n0 + tx * 4 + 3];
    }
#pragma unroll
    for (int i = 0; i < 4; i++) {
        float4 ov;
        ov.x = acc[i][0] + b0; ov.y = acc[i][1] + b1;
        ov.z = acc[i][2] + b2; ov.w = acc[i][3] + b3;
        *(float4*)&C[(size_t)(m0 + ty * 4 + i) * Nc + n0 + tx * 4] = ov;
    }
}

// ---------------------------------------------------------------------------
// dot_kq: kq[m] = dot(kp[m,:], qp[m,:]) over D=512 — state-independent, so
// hoisted out of the sequential scan. One wave per row, 4 waves per block.
__global__ __launch_bounds__(256)
void dot_kq(const float* __restrict__ kp, const float* __restrict__ qp,
            float* __restrict__ kq) {
    const int m = blockIdx.x * 4 + (threadIdx.x >> 6);
    const int lane = threadIdx.x & 63;
    const float* kr = kp + (size_t)m * D_SZ + lane * 8;
    const float* qr = qp + (size_t)m * D_SZ + lane * 8;
    float acc = 0.f;
#pragma unroll
    for (int j = 0; j < 2; j++) {
        float4 kv = *(const float4*)&kr[j * 4];
        float4 qv = *(const float4*)&qr[j * 4];
        acc += kv.x * qv.x + kv.y * qv.y + kv.z * qv.z + kv.w * qv.w;
    }
    acc += __shfl_xor(acc, 1, 64);
    acc += __shfl_xor(acc, 2, 64);
    acc += __shfl_xor(acc, 4, 64);
    acc += __shfl_xor(acc, 8, 64);
    acc += __shfl_xor(acc, 16, 64);
    acc += __shfl_xor(acc, 32, 64);
    if (lane == 0) kq[m] = acc;
}

// ---------------------------------------------------------------------------
// scan_kernel v3: one 1024-thread block per batch (8 blocks).
// __launch_bounds__(1024, 4): 4 waves/SIMD = 1 block/CU -> 128-VGPR budget.
// (v2's plain (1024) capped VGPRs at 64 = exactly s[]+kr[], forcing AGPR
// spill-copy traffic for everything else -> 5x VALU inflation.)
// Thread (n = tid>>4, c = tid&15) owns a 32-wide d-chunk of state row n.
// kq = k.q precomputed by dot_kq; y = tanh(alpha*(S.q) + g*kq).
__global__ __launch_bounds__(1024, 4)
void scan_kernel(const float* __restrict__ kp, const float* __restrict__ qp,
                 const float* __restrict__ wxp, const float* __restrict__ axp,
                 const float* __restrict__ kqp, const float* __restrict__ S0,
                 const float* __restrict__ W_r,
                 float* __restrict__ out_y, float2* __restrict__ coef) {
    const int b = blockIdx.x;
    const int tid = threadIdx.x;          // 0..1023
    const int n = tid >> 4;               // 0..63
    const int c = tid & 15;               // 0..15
    const int d0 = c * 32;

    __shared__ float bufK[2][512];
    __shared__ float bufQ[2][512];
    __shared__ float sh_r[2][64];

    // W_r fragment: constant across steps -> registers, no LDS staging
    const float wr0 = W_r[n * 64 + c * 4 + 0];
    const float wr1 = W_r[n * 64 + c * 4 + 1];
    const float wr2 = W_r[n * 64 + c * 4 + 2];
    const float wr3 = W_r[n * 64 + c * 4 + 3];

    // state chunk
    float s[32];
    {
        const float* s0p = S0 + ((size_t)b * N_SZ + n) * D_SZ + d0;
#pragma unroll
        for (int j = 0; j < 8; j++) {
            float4 v4 = *(const float4*)&s0p[j * 4];
            s[j * 4 + 0] = v4.x; s[j * 4 + 1] = v4.y;
            s[j * 4 + 2] = v4.z; s[j * 4 + 3] = v4.w;
        }
    }

    // prologue: fill buf[0] with k_0/q_0; preload wx/ax/kq for t=0
    {
        float p0 = (tid < 512) ? kp[(size_t)b * D_SZ + tid]
                               : qp[(size_t)b * D_SZ + (tid - 512)];
        if (tid < 512) bufK[0][swz(tid)] = p0;
        else           bufQ[0][swz(tid - 512)] = p0;
    }
    float wxr = wxp[(size_t)b * N_SZ + n];
    float axr = axp[(size_t)b * N_SZ + n];
    float kqr = kqp[b];
    __syncthreads();

    for (int t = 0; t < T_STEPS; t++) {
        const int cur = t & 1, nxt = cur ^ 1;
        const size_t tb = (size_t)t * B_SZ + b;
        const int t1 = (t + 1 < T_STEPS) ? (t + 1) : t;
        const size_t tb1 = (size_t)t1 * B_SZ + b;

        // ---- prefetch next step's inputs (latency hides under the dots) ----
        float pk  = (tid < 512) ? kp[tb1 * D_SZ + tid]
                                : qp[tb1 * D_SZ + (tid - 512)];
        float nwx = wxp[tb1 * N_SZ + n];
        float nax = axp[tb1 * N_SZ + n];
        float nkq = kqp[tb1];

        // ---- k chunk + sk = S.k ----
        float kr[32];
        float sk0 = 0.f, sk1 = 0.f, sk2 = 0.f, sk3 = 0.f;
#pragma unroll
        for (int j = 0; j < 8; j++) {
            float4 kv = *(const float4*)&bufK[cur][swz(d0 + j * 4)];
            kr[j * 4 + 0] = kv.x; kr[j * 4 + 1] = kv.y;
            kr[j * 4 + 2] = kv.z; kr[j * 4 + 3] = kv.w;
            sk0 += s[j * 4 + 0] * kv.x; sk1 += s[j * 4 + 1] * kv.y;
            sk2 += s[j * 4 + 2] * kv.z; sk3 += s[j * 4 + 3] * kv.w;
        }
        // ---- stream q: sq = S.q (kq precomputed by dot_kq) ----
        float sq0 = 0.f, sq1 = 0.f, sq2 = 0.f, sq3 = 0.f;
#pragma unroll
        for (int j = 0; j < 8; j++) {
            float4 qv = *(const float4*)&bufQ[cur][swz(d0 + j * 4)];
            sq0 += s[j * 4 + 0] * qv.x; sq1 += s[j * 4 + 1] * qv.y;
            sq2 += s[j * 4 + 2] * qv.z; sq3 += s[j * 4 + 3] * qv.w;
        }
        float sk = red16(sk0 + sk1 + sk2 + sk3);
        float sq = red16(sq0 + sq1 + sq2 + sq3);
        float retr = tanh_fast(sk);
        if (c == 0) sh_r[cur][n] = retr;

        // ---- stage next k/q into the other buffer (pre-barrier) ----
        if (tid < 512) bufK[nxt][swz(tid)] = pk;
        else           bufQ[nxt][swz(tid - 512)] = pk;

        __syncthreads();   // the ONLY barrier per step

        // ---- v[n] = tanh( sum_m retr[m]*W_r[n,m] + wx ) ----
        float4 rr = *(const float4*)&sh_r[cur][c * 4];
        float vp = red16(wr0 * rr.x + wr1 * rr.y + wr2 * rr.z + wr3 * rr.w);
        float v = tanh_fast(vp + wxr);
        float alpha = 1.f / (1.f + __expf(-axr));
        float g = (1.f - alpha) * v;

        // ---- state update: S = alpha*S + g*k ----
#pragma unroll
        for (int j = 0; j < 32; j++) s[j] = alpha * s[j] + g * kr[j];

        // ---- y = tanh(S_new.q) = tanh(alpha*(S.q) + g*(k.q)) ----
        if (c == 0) {
            out_y[tb * N_SZ + n] = tanh_fast(alpha * sq + g * kqr);
            coef[tb * N_SZ + n] = make_float2(alpha, g);
        }
        wxr = nwx; axr = nax; kqr = nkq;
    }
}

// ---------------------------------------------------------------------------
// reconstruct_S: replay S_t[n,d] = alpha_t[n]*S_{t-1}[n,d] + g_t[n]*k_t[d]
// (unchanged — elementwise-parallel, streams 537 MB at device write BW)
__global__ __launch_bounds__(256)
void reconstruct_S(const float* __restrict__ kp, const float2* __restrict__ coef,
                   const float* __restrict__ S0, float* __restrict__ out_S) {
    const int tid = blockIdx.x * 256 + threadIdx.x;  // 0 .. 65535
    const int dq = tid & 127;          // d/4 within row
    const int n  = (tid >> 7) & 63;
    const int b  = tid >> 13;
    const size_t nd_off = ((size_t)b * N_SZ + n) * D_SZ + (size_t)dq * 4;
    const size_t step_S = (size_t)B_SZ * N_SZ * D_SZ;  // 262144 floats per t

    float4 s = *(const float4*)&S0[nd_off];
    *(float4*)&out_S[nd_off] = s;      // t = 0 slice
#pragma unroll 4
    for (int t = 0; t < T_STEPS; t++) {
        const size_t tb = (size_t)t * B_SZ + b;
        float2 ag = coef[tb * N_SZ + n];
        float4 kv = *(const float4*)&kp[tb * D_SZ + (size_t)dq * 4];
        s.x = ag.x * s.x + ag.y * kv.x;
        s.y = ag.x * s.y + ag.y * kv.y;
        s.z = ag.x * s.z + ag.y * kv.z;
        s.w = ag.x * s.w + ag.y * kv.w;
        *(float4*)&out_S[(size_t)(t + 1) * step_S + nd_off] = s;
    }
}

// ---------------------------------------------------------------------------
extern "C" void kernel_launch(void* const* d_in, const int* in_sizes, int n_in,
                              void* d_out, int out_size, void* d_ws, size_t ws_size,
                              hipStream_t stream) {
    const float* x       = (const float*)d_in[0];  // [T,B,D]
    const float* S0      = (const float*)d_in[1];  // [B,N,D]
    const float* W_k     = (const float*)d_in[2];  // [D,D]
    const float* W_q     = (const float*)d_in[3];  // [D,D]
    const float* W_x     = (const float*)d_in[4];  // [N,D]
    const float* W_r     = (const float*)d_in[5];  // [N,N]
    const float* b       = (const float*)d_in[6];  // [N]
    const float* W_alpha = (const float*)d_in[7];  // [N,D]
    const float* b_alpha = (const float*)d_in[8];  // [N]

    float* out_y = (float*)d_out;                              // [T,B,N]
    float* out_S = out_y + (size_t)T_STEPS * B_SZ * N_SZ;      // [T+1,B,N,D]

    const int M = T_STEPS * B_SZ;  // 4096
    float*  kp   = (float*)d_ws;                      // [M, D]
    float*  qp   = kp + (size_t)M * D_SZ;             // [M, D]
    float*  wxp  = qp + (size_t)M * D_SZ;             // [M, N]  (b folded)
    float*  axp  = wxp + (size_t)M * N_SZ;            // [M, N]  (b_alpha folded)
    float2* coef = (float2*)(axp + (size_t)M * N_SZ); // [M, N] float2(alpha, g)
    float*  kqp  = (float*)(coef + (size_t)M * N_SZ); // [M]    k_t . q_t

    // projections
    {
        dim3 blk(256);
        dim3 gK(M / 64, D_SZ / 64);
        proj_gemm<<<gK, blk, 0, stream>>>(x, W_k, nullptr, kp, M, D_SZ, D_SZ);
        proj_gemm<<<gK, blk, 0, stream>>>(x, W_q, nullptr, qp, M, D_SZ, D_SZ);
        dim3 gN(M / 64, N_SZ / 64);
        proj_gemm<<<gN, blk, 0, stream>>>(x, W_x, b, wxp, M, N_SZ, D_SZ);
        proj_gemm<<<gN, blk, 0, stream>>>(x, W_alpha, b_alpha, axp, M, N_SZ, D_SZ);
    }

    // state-independent dot products k_t . q_t (hoisted out of the scan)
    dot_kq<<<dim3(M / 4), dim3(256), 0, stream>>>(kp, qp, kqp);

    // sequential scan: one 1024-thread workgroup per batch
    scan_kernel<<<dim3(B_SZ), dim3(1024), 0, stream>>>(
        kp, qp, wxp, axp, kqp, S0, W_r, out_y, coef);

    // parallel replay of the (now linear) recurrence: writes all of out_S
    reconstruct_S<<<dim3((B_SZ * N_SZ * D_SZ / 4) / 256), dim3(256), 0, stream>>>(
        kp, coef, S0, out_S);
}

// Round 4
// 1464.223 us; speedup vs baseline: 4.7640x; 1.1746x over previous
//
#include <hip/hip_runtime.h>
#include <math.h>

#define T_STEPS 512
#define B_SZ 8
#define D_SZ 512
#define N_SZ 64

// ---------------------------------------------------------------------------
// fast tanh via hardware exp; clamp avoids inf/inf NaN
__device__ __forceinline__ float tanh_fast(float x) {
    float cx = fminf(30.f, fmaxf(-30.f, x));
    float e = __expf(2.f * cx);
    return (e - 1.f) / (e + 1.f);
}

// ---------------------------------------------------------------------------
// DPP rotate-reduce across a 16-lane row (= the c-group: lane bits 0..3).
// row_ror:N = dpp_ctrl 0x120|N. Pure VALU — no LDS pipe, unlike __shfl_xor.
template <int CTRL>
__device__ __forceinline__ float ror_add(float x) {
    int r = __builtin_amdgcn_update_dpp(0, __float_as_int(x), CTRL, 0xf, 0xf, false);
    return x + __int_as_float(r);
}
__device__ __forceinline__ float red16_dpp(float x) {
    x = ror_add<0x121>(x);   // ror 1
    x = ror_add<0x122>(x);   // ror 2
    x = ror_add<0x124>(x);   // ror 4
    x = ror_add<0x128>(x);   // ror 8  -> every lane holds the 16-lane sum
    return x;
}

// XOR swizzle for the 512-word k LDS buffer (16-way -> 2-way bank conflict).
__device__ __forceinline__ int swz(int w) {
    return w ^ (((w >> 5) & 7) << 2);
}

// ---------------------------------------------------------------------------
// proj_gemm: C[m,n] = sum_d A[m,d] * W[n,d] (+ bias[n]; act==1 -> sigmoid)
__global__ __launch_bounds__(256)
void proj_gemm(const float* __restrict__ A, const float* __restrict__ W,
               const float* __restrict__ bias, float* __restrict__ C,
               int M, int Nc, int D, int act) {
    __shared__ float As[16][64];
    __shared__ float Ws[16][64];
    const int m0 = blockIdx.x * 64;
    const int n0 = blockIdx.y * 64;
    const int tid = threadIdx.x;
    const int tx = tid & 15;        // n direction
    const int ty = tid >> 4;        // m direction
    const int lr = tid >> 2;        // 0..63 row within tile (for loading)
    const int lk = (tid & 3) * 4;   // k offset within tile

    float acc[4][4];
#pragma unroll
    for (int i = 0; i < 4; i++)
#pragma unroll
        for (int j = 0; j < 4; j++) acc[i][j] = 0.f;

    for (int kk = 0; kk < D; kk += 16) {
        float4 av = *(const float4*)&A[(size_t)(m0 + lr) * D + kk + lk];
        float4 wv = *(const float4*)&W[(size_t)(n0 + lr) * D + kk + lk];
        __syncthreads();
        As[lk + 0][lr] = av.x; As[lk + 1][lr] = av.y;
        As[lk + 2][lr] = av.z; As[lk + 3][lr] = av.w;
        Ws[lk + 0][lr] = wv.x; Ws[lk + 1][lr] = wv.y;
        Ws[lk + 2][lr] = wv.z; Ws[lk + 3][lr] = wv.w;
        __syncthreads();
#pragma unroll
        for (int k = 0; k < 16; k++) {
            float a0 = As[k][ty * 4 + 0], a1 = As[k][ty * 4 + 1];
            float a2 = As[k][ty * 4 + 2], a3 = As[k][ty * 4 + 3];
            float w0 = Ws[k][tx * 4 + 0], w1 = Ws[k][tx * 4 + 1];
            float w2 = Ws[k][tx * 4 + 2], w3 = Ws[k][tx * 4 + 3];
            acc[0][0] += a0 * w0; acc[0][1] += a0 * w1; acc[0][2] += a0 * w2; acc[0][3] += a0 * w3;
            acc[1][0] += a1 * w0; acc[1][1] += a1 * w1; acc[1][2] += a1 * w2; acc[1][3] += a1 * w3;
            acc[2][0] += a2 * w0; acc[2][1] += a2 * w1; acc[2][2] += a2 * w2; acc[2][3] += a2 * w3;
            acc[3][0] += a3 * w0; acc[3][1] += a3 * w1; acc[3][2] += a3 * w2; acc[3][3] += a3 * w3;
        }
    }

    float b0 = 0.f, b1 = 0.f, b2 = 0.f, b3 = 0.f;
    if (bias) {
        b0 = bias[n0 + tx * 4 + 0]; b1 = bias[n0 + tx * 4 + 1];
        b2 = bias[n0 + tx * 4 + 2]; b3 = bias[n0 + tx * 4 + 3];
    }
#pragma unroll
    for (int i = 0; i < 4; i++) {
        float4 ov;
        ov.x = acc[i][0] + b0; ov.y = acc[i][1] + b1;
        ov.z = acc[i][2] + b2; ov.w = acc[i][3] + b3;
        if (act == 1) {   // sigmoid epilogue (for the alpha projection)
            ov.x = 1.f / (1.f + __expf(-ov.x));
            ov.y = 1.f / (1.f + __expf(-ov.y));
            ov.z = 1.f / (1.f + __expf(-ov.z));
            ov.w = 1.f / (1.f + __expf(-ov.w));
        }
        *(float4*)&C[(size_t)(m0 + ty * 4 + i) * Nc + n0 + tx * 4] = ov;
    }
}

// ---------------------------------------------------------------------------
// scan_kernel v4: one 1024-thread block per batch (8 blocks).
// Minimal per-step job: sk = S.k -> retr -> v -> (alpha,g) -> S update.
// y is computed post-hoc (compute_y) from reconstructed S; q never enters.
// No kr[] registers: the update re-reads k from the SAME LDS buffer
// post-barrier. bufK is TRIPLE-buffered so step t+2's staging write to
// buf[t%3] is fenced from step t's post-barrier read by the t+1 barrier.
// Live set ~50 VGPR -> fits the 64-VGPR allocation with zero spills.
// Reductions are DPP row_ror (16-lane rows == c-groups), pure VALU.
__global__ __launch_bounds__(1024, 4)
void scan_kernel(const float* __restrict__ kp, const float* __restrict__ wxp,
                 const float* __restrict__ alp, const float* __restrict__ S0,
                 const float* __restrict__ W_r, float2* __restrict__ coef) {
    const int b = blockIdx.x;
    const int tid = threadIdx.x;          // 0..1023
    const int n = tid >> 4;               // 0..63
    const int c = tid & 15;               // 0..15
    const int d0 = c * 32;
    const int sxor = (c & 7) << 2;        // swizzle xor for this thread's chunk

    __shared__ float bufK[3][512];
    __shared__ float sh_r[2][64];

    // W_r fragment: constant across steps -> registers
    const float wr0 = W_r[n * 64 + c * 4 + 0];
    const float wr1 = W_r[n * 64 + c * 4 + 1];
    const float wr2 = W_r[n * 64 + c * 4 + 2];
    const float wr3 = W_r[n * 64 + c * 4 + 3];

    // state chunk
    float s[32];
    {
        const float* s0p = S0 + ((size_t)b * N_SZ + n) * D_SZ + d0;
#pragma unroll
        for (int j = 0; j < 8; j++) {
            float4 v4 = *(const float4*)&s0p[j * 4];
            s[j * 4 + 0] = v4.x; s[j * 4 + 1] = v4.y;
            s[j * 4 + 2] = v4.z; s[j * 4 + 3] = v4.w;
        }
    }

    // prologue: buf[0] <- k_0; pk <- k_1; wx/alpha for t=0
    if (tid < 512) bufK[0][swz(tid)] = kp[(size_t)b * D_SZ + tid];
    float pk = (tid < 512) ? kp[((size_t)1 * B_SZ + b) * D_SZ + tid] : 0.f;
    float wxr = wxp[(size_t)b * N_SZ + n];
    float alr = alp[(size_t)b * N_SZ + n];
    __syncthreads();

    int cur = 0;
    for (int t = 0; t < T_STEPS; t++) {
        const size_t tb = (size_t)t * B_SZ + b;
        const int nx1 = (cur == 2) ? 0 : cur + 1;
        const int t1 = (t + 1 < T_STEPS) ? (t + 1) : t;
        const int t2 = (t + 2 < T_STEPS) ? (t + 2) : t;

        // ---- prefetch: k_{t+2} (2-deep, full step of latency cover) ----
        float pk2 = (tid < 512) ? kp[((size_t)t2 * B_SZ + b) * D_SZ + tid] : 0.f;
        float nwx = wxp[(size_t)t1 * B_SZ * N_SZ + b * N_SZ + n];
        float nal = alp[(size_t)t1 * B_SZ * N_SZ + b * N_SZ + n];

        // ---- sk = S.k (k from swizzled LDS) ----
        float sk0 = 0.f, sk1 = 0.f, sk2 = 0.f, sk3 = 0.f;
#pragma unroll
        for (int j = 0; j < 8; j++) {
            float4 kv = *(const float4*)&bufK[cur][d0 + ((j * 4) ^ sxor)];
            sk0 += s[j * 4 + 0] * kv.x; sk1 += s[j * 4 + 1] * kv.y;
            sk2 += s[j * 4 + 2] * kv.z; sk3 += s[j * 4 + 3] * kv.w;
        }
        float sk = red16_dpp(sk0 + sk1 + sk2 + sk3);
        float retr = tanh_fast(sk);
        if (c == 0) sh_r[t & 1][n] = retr;

        // ---- stage k_{t+1} (loaded last step) into the next buffer ----
        if (tid < 512) bufK[nx1][swz(tid)] = pk;

        __syncthreads();   // the ONLY barrier per step

        // ---- v[n] = tanh( sum_m retr[m]*W_r[n,m] + wx ) ----
        float4 rr = *(const float4*)&sh_r[t & 1][c * 4];
        float vp = red16_dpp(wr0 * rr.x + wr1 * rr.y + wr2 * rr.z + wr3 * rr.w);
        float v = tanh_fast(vp + wxr);
        float g = (1.f - alr) * v;      // alr = sigmoid(ax), precomputed

        // ---- state update: S = alpha*S + g*k (k re-read from LDS) ----
#pragma unroll
        for (int j = 0; j < 8; j++) {
            float4 kv = *(const float4*)&bufK[cur][d0 + ((j * 4) ^ sxor)];
            s[j * 4 + 0] = alr * s[j * 4 + 0] + g * kv.x;
            s[j * 4 + 1] = alr * s[j * 4 + 1] + g * kv.y;
            s[j * 4 + 2] = alr * s[j * 4 + 2] + g * kv.z;
            s[j * 4 + 3] = alr * s[j * 4 + 3] + g * kv.w;
        }
        if (c == 0) coef[tb * N_SZ + n] = make_float2(alr, g);

        wxr = nwx; alr = nal; pk = pk2; cur = nx1;
    }
}

// ---------------------------------------------------------------------------
// reconstruct_S: replay S_t[n,d] = alpha_t[n]*S_{t-1}[n,d] + g_t[n]*k_t[d]
// (elementwise-parallel, streams 537 MB at device write BW)
__global__ __launch_bounds__(256)
void reconstruct_S(const float* __restrict__ kp, const float2* __restrict__ coef,
                   const float* __restrict__ S0, float* __restrict__ out_S) {
    const int tid = blockIdx.x * 256 + threadIdx.x;  // 0 .. 65535
    const int dq = tid & 127;          // d/4 within row
    const int n  = (tid >> 7) & 63;
    const int b  = tid >> 13;
    const size_t nd_off = ((size_t)b * N_SZ + n) * D_SZ + (size_t)dq * 4;
    const size_t step_S = (size_t)B_SZ * N_SZ * D_SZ;  // 262144 floats per t

    float4 s = *(const float4*)&S0[nd_off];
    *(float4*)&out_S[nd_off] = s;      // t = 0 slice
#pragma unroll 4
    for (int t = 0; t < T_STEPS; t++) {
        const size_t tb = (size_t)t * B_SZ + b;
        float2 ag = coef[tb * N_SZ + n];
        float4 kv = *(const float4*)&kp[tb * D_SZ + (size_t)dq * 4];
        s.x = ag.x * s.x + ag.y * kv.x;
        s.y = ag.x * s.y + ag.y * kv.y;
        s.z = ag.x * s.z + ag.y * kv.z;
        s.w = ag.x * s.w + ag.y * kv.w;
        *(float4*)&out_S[(size_t)(t + 1) * step_S + nd_off] = s;
    }
}

// ---------------------------------------------------------------------------
// compute_y: y[t,b,n] = tanh( dot(S[t+1,b,n,:], q[t,b,:]) ).
// One wave per (t,b,n) row: lane reads 8 floats of S + 8 of q, 6-stage
// shuffle reduce. 262144 waves over 256 CUs; HBM-bound on the 537 MB S read
// (much of it LLC-resident right after reconstruct_S wrote it).
__global__ __launch_bounds__(256)
void compute_y(const float* __restrict__ out_S, const float* __restrict__ qp,
               float* __restrict__ out_y) {
    const int gw = (blockIdx.x * 256 + threadIdx.x) >> 6;  // global wave id
    const int lane = threadIdx.x & 63;
    const int n = gw & 63;
    const int b = (gw >> 6) & 7;
    const int t = gw >> 9;
    const float* srow = out_S + ((size_t)(t + 1) * B_SZ * N_SZ
                                 + (size_t)b * N_SZ + n) * D_SZ + lane * 8;
    const float* qrow = qp + ((size_t)t * B_SZ + b) * D_SZ + lane * 8;

    float4 s0 = *(const float4*)&srow[0];
    float4 s1 = *(const float4*)&srow[4];
    float4 q0 = *(const float4*)&qrow[0];
    float4 q1 = *(const float4*)&qrow[4];
    float acc = s0.x * q0.x + s0.y * q0.y + s0.z * q0.z + s0.w * q0.w
              + s1.x * q1.x + s1.y * q1.y + s1.z * q1.z + s1.w * q1.w;
    acc += __shfl_xor(acc, 1, 64);
    acc += __shfl_xor(acc, 2, 64);
    acc += __shfl_xor(acc, 4, 64);
    acc += __shfl_xor(acc, 8, 64);
    acc += __shfl_xor(acc, 16, 64);
    acc += __shfl_xor(acc, 32, 64);
    if (lane == 0)
        out_y[((size_t)t * B_SZ + b) * N_SZ + n] = tanh_fast(acc);
}

// ---------------------------------------------------------------------------
extern "C" void kernel_launch(void* const* d_in, const int* in_sizes, int n_in,
                              void* d_out, int out_size, void* d_ws, size_t ws_size,
                              hipStream_t stream) {
    const float* x       = (const float*)d_in[0];  // [T,B,D]
    const float* S0      = (const float*)d_in[1];  // [B,N,D]
    const float* W_k     = (const float*)d_in[2];  // [D,D]
    const float* W_q     = (const float*)d_in[3];  // [D,D]
    const float* W_x     = (const float*)d_in[4];  // [N,D]
    const float* W_r     = (const float*)d_in[5];  // [N,N]
    const float* b       = (const float*)d_in[6];  // [N]
    const float* W_alpha = (const float*)d_in[7];  // [N,D]
    const float* b_alpha = (const float*)d_in[8];  // [N]

    float* out_y = (float*)d_out;                              // [T,B,N]
    float* out_S = out_y + (size_t)T_STEPS * B_SZ * N_SZ;      // [T+1,B,N,D]

    const int M = T_STEPS * B_SZ;  // 4096
    float*  kp   = (float*)d_ws;                      // [M, D]
    float*  qp   = kp + (size_t)M * D_SZ;             // [M, D]
    float*  wxp  = qp + (size_t)M * D_SZ;             // [M, N]  (b folded)
    float*  alp  = wxp + (size_t)M * N_SZ;            // [M, N]  alpha = sigmoid(ax)
    float2* coef = (float2*)(alp + (size_t)M * N_SZ); // [M, N]  float2(alpha, g)

    // projections (alpha projection gets the sigmoid epilogue)
    {
        dim3 blk(256);
        dim3 gK(M / 64, D_SZ / 64);
        proj_gemm<<<gK, blk, 0, stream>>>(x, W_k, nullptr, kp, M, D_SZ, D_SZ, 0);
        proj_gemm<<<gK, blk, 0, stream>>>(x, W_q, nullptr, qp, M, D_SZ, D_SZ, 0);
        dim3 gN(M / 64, N_SZ / 64);
        proj_gemm<<<gN, blk, 0, stream>>>(x, W_x, b, wxp, M, N_SZ, D_SZ, 0);
        proj_gemm<<<gN, blk, 0, stream>>>(x, W_alpha, b_alpha, alp, M, N_SZ, D_SZ, 1);
    }

    // sequential scan: emits ONLY the (alpha, g) coefficients
    scan_kernel<<<dim3(B_SZ), dim3(1024), 0, stream>>>(
        kp, wxp, alp, S0, W_r, coef);

    // parallel replay of the (now linear) recurrence: writes all of out_S
    reconstruct_S<<<dim3((B_SZ * N_SZ * D_SZ / 4) / 256), dim3(256), 0, stream>>>(
        kp, coef, S0, out_S);

    // y from reconstructed S (one wave per (t,b,n) row)
    compute_y<<<dim3((size_t)T_STEPS * B_SZ * N_SZ * 64 / 256), dim3(256), 0, stream>>>(
        out_S, qp, out_y);
}